// Round 5
// baseline (224.573 us; speedup 1.0000x reference)
//
#include <hip/hip_runtime.h>
#include <hip/hip_bf16.h>

#define B_DIM 32
#define T_DIM 2048
#define D_DIM 1024
#define S_MAXK 32
#define LSTR  256   // max matches per (b,s); mean 62, sd 7.8 -> 256 is +25 sigma

// ws layout (bytes):
//   h    float[B][32][D] @ 0       : 4,194,304  (mean |x| per (b,step))
//   pos  uint [B][32]    @ 4194304 : 4,096
//   ctrl float[2]+uint   @ 4198400 : 12         (tot, num, done_b)
//   bdone uint[B]        @ 4198528 : 128
#define H_OFF    0
#define POS_OFF  4194304
#define CTRL_OFF 4198400
#define BDONE_OFF 4198528

// Single fused kernel: one block per (b,step).
// Phase 1: scan sid row -> LDS match list (+count+firstpos). Phase 2: 8-deep
// batched float4 gather of |x| rows, write h = mean. Phase 3: last block of
// each b (device-scope done counter) runs the per-b pair/loss logic inline;
// last b overall writes the final scalar. No spin-waits anywhere.
__global__ __launch_bounds__(256) void k_fused(const float* __restrict__ x,
                                               const int* __restrict__ sid,
                                               const int* __restrict__ labels,
                                               float* __restrict__ h,
                                               unsigned* __restrict__ pos,
                                               unsigned* __restrict__ bdone,
                                               float* __restrict__ ctrl,
                                               float* __restrict__ out) {
    __shared__ int      list[LSTR];
    __shared__ int      cnt;
    __shared__ unsigned firstpos;
    __shared__ int      sh_last;
    __shared__ unsigned posl[32];
    __shared__ int      ordl[32];
    __shared__ float    El[31];

    const int b = blockIdx.x >> 5;
    const int s = blockIdx.x & 31;
    const int tid = threadIdx.x;

    if (tid == 0) { cnt = 0; firstpos = 0xFFFFFFFFu; }
    __syncthreads();

    // ---- phase 1: scan (8 unrolled L2-shared loads + tiny LDS-atomic tail)
    const int* srow = sid + b * T_DIM;
    unsigned myfirst = 0xFFFFFFFFu;
    #pragma unroll
    for (int t = tid; t < T_DIM; t += 256) {
        if (srow[t] == s + 1) {
            int idx = atomicAdd(&cnt, 1);
            if (idx < LSTR) list[idx] = t;
            if ((unsigned)t < myfirst) myfirst = (unsigned)t;
        }
    }
    if (myfirst != 0xFFFFFFFFu) atomicMin(&firstpos, myfirst);
    __syncthreads();

    // ---- phase 2: gather
    const int ntrue = cnt;
    const int n = ntrue < LSTR ? ntrue : LSTR;
    const float4* xb = (const float4*)(x + (size_t)b * T_DIM * D_DIM);
    float4 acc = {0.f, 0.f, 0.f, 0.f};

    int i = 0;
    for (; i + 8 <= n; i += 8) {
        float4 v[8];
        #pragma unroll
        for (int j = 0; j < 8; ++j)
            v[j] = xb[(size_t)list[i + j] * (D_DIM / 4) + tid];
        #pragma unroll
        for (int j = 0; j < 8; ++j) {
            acc.x += fabsf(v[j].x); acc.y += fabsf(v[j].y);
            acc.z += fabsf(v[j].z); acc.w += fabsf(v[j].w);
        }
    }
    for (; i < n; ++i) {
        float4 v = xb[(size_t)list[i] * (D_DIM / 4) + tid];
        acc.x += fabsf(v.x); acc.y += fabsf(v.y);
        acc.z += fabsf(v.z); acc.w += fabsf(v.w);
    }

    const float r = 1.0f / (float)(ntrue > 1 ? ntrue : 1);
    ((float4*)(h + (size_t)blockIdx.x * D_DIM))[tid] =
        make_float4(acc.x * r, acc.y * r, acc.z * r, acc.w * r);
    if (tid == 0) pos[blockIdx.x] = (ntrue > 0) ? firstpos : (unsigned)T_DIM;

    // release h/pos to device scope, then count this block done for its b
    __threadfence();
    __syncthreads();
    if (tid == 0) {
        unsigned old = atomicAdd(&bdone[b], 1u);
        sh_last = (old == 31u) ? 1 : 0;
    }
    __syncthreads();
    if (!sh_last) return;

    // ---- phase 3: this is the last block of b -> per-b pairs + loss
    __threadfence();   // acquire: make siblings' h/pos visible
    if (tid < 32) posl[tid] = pos[(b << 5) + tid];
    __syncthreads();
    if (tid < 32) {                     // stable argsort of pos
        unsigned ps = posl[tid];
        int rk = 0;
        for (int j = 0; j < 32; ++j) {
            unsigned pj = posl[j];
            if (pj < ps || (pj == ps && j < tid)) rk++;
        }
        ordl[rk] = tid;
    }
    __syncthreads();

    const int wave = tid >> 6;
    const int lane = tid & 63;
    for (int p = wave; p < 31; p += 4) {
        int A  = ordl[p];
        int B2 = ordl[p + 1];
        float ssum = 0.0f;
        if (posl[B2] < (unsigned)T_DIM) {
            const float* pa = &h[((size_t)(b << 5) + A)  * D_DIM];
            const float* pb = &h[((size_t)(b << 5) + B2) * D_DIM];
            for (int d = lane * 4; d < D_DIM; d += 256) {
                float4 a4 = *(const float4*)(pa + d);
                float4 b4 = *(const float4*)(pb + d);
                float d0 = fmaxf(a4.x - b4.x, 0.f);
                float d1 = fmaxf(a4.y - b4.y, 0.f);
                float d2 = fmaxf(a4.z - b4.z, 0.f);
                float d3 = fmaxf(a4.w - b4.w, 0.f);
                ssum += d0 * d0 + d1 * d1 + d2 * d2 + d3 * d3;
            }
        }
        #pragma unroll
        for (int off = 32; off; off >>= 1) ssum += __shfl_down(ssum, off);
        if (lane == 0) El[p] = ssum * (1.0f / D_DIM);
    }
    __syncthreads();

    if (tid == 0) {
        float lpos = 0.f, lneg = 0.f;
        int np = 0, ni = 0, nn = 0;
        for (int s2 = 0; s2 < 32; ++s2) nn += (posl[s2] < T_DIM) ? 1 : 0;
        for (int p = 0; p < 31; ++p) {
            int A  = ordl[p];
            int B2 = ordl[p + 1];
            if (posl[B2] < (unsigned)T_DIM) {      // pair_valid
                float Ev = El[p];
                np++; lpos += Ev;
                if (A > B2) { ni++; lneg += fmaxf(1.0f - Ev, 0.0f); }  // ALPHA=1
            }
        }
        float loss_pos = lpos / (float)(np > 1 ? np : 1);
        float loss_neg = lneg / (float)(ni > 1 ? ni : 1);
        int lab = labels[b];
        bool pc = (lab == 1) && (nn >= 2);
        bool nc = (lab == 0) && (ni > 0);
        float contrib = (pc ? loss_pos : 0.0f) + (nc ? loss_neg : 0.0f);
        float cf = (float)((pc ? 1 : 0) + (nc ? 1 : 0));

        atomicAdd(&ctrl[0], contrib);
        atomicAdd(&ctrl[1], cf);
        __threadfence();
        unsigned old2 = atomicAdd(&((unsigned*)ctrl)[2], 1u);
        if (old2 == (unsigned)(B_DIM - 1)) {       // last b overall
            __threadfence();
            float tot = atomicAdd(&ctrl[0], 0.0f); // coherent reads
            float num = atomicAdd(&ctrl[1], 0.0f);
            out[0] = tot / (num + 1e-9f);
        }
    }
}

extern "C" void kernel_launch(void* const* d_in, const int* in_sizes, int n_in,
                              void* d_out, int out_size, void* d_ws, size_t ws_size,
                              hipStream_t stream) {
    const float* x      = (const float*)d_in[0];
    const int*   sid    = (const int*)d_in[1];
    const int*   labels = (const int*)d_in[2];
    float* out = (float*)d_out;
    char*  ws  = (char*)d_ws;

    float*    h     = (float*)(ws + H_OFF);
    unsigned* pos   = (unsigned*)(ws + POS_OFF);
    float*    ctrl  = (float*)(ws + CTRL_OFF);
    unsigned* bdone = (unsigned*)(ws + BDONE_OFF);

    // reset done-counters + accumulators (tiny, graph-capturable)
    hipMemsetAsync(ws + CTRL_OFF, 0, 256, stream);

    k_fused<<<B_DIM * S_MAXK, 256, 0, stream>>>(x, sid, labels, h, pos, bdone, ctrl, out);
}

// Round 6
// 70.797 us; speedup vs baseline: 3.1721x; 3.1721x over previous
//
#include <hip/hip_runtime.h>
#include <hip/hip_bf16.h>

#define B_DIM 32
#define T_DIM 2048
#define D_DIM 1024
#define S_MAXK 32

// ws layout (bytes):
//   h    float[B][32][D] @ 0       : 4,194,304  (mean |x| per (b,step))
//   pos  uint [B][32]    @ 4194304 : 4,096
//   ctrl {float tot, float num, uint done} @ 4198400
#define H_OFF    0
#define POS_OFF  4194304
#define CTRL_OFF 4198400

// One block per (b, step). Phase 1: scan sid row -> LDS match list (count +
// first pos, LDS atomics only). Phase 2: 8-deep EXPLICITLY NAMED batched
// float4 loads (forces 32 data VGPRs -> 8 loads in flight per thread).
// Keep this kernel minimal: no fences, no sorts, so regalloc stays generous.
__global__ __launch_bounds__(256) void k_gather(const float* __restrict__ x,
                                                const int* __restrict__ sid,
                                                float* __restrict__ h,
                                                unsigned* __restrict__ pos,
                                                float* __restrict__ ctrl) {
    __shared__ int      list[T_DIM];
    __shared__ int      cnt;
    __shared__ unsigned firstpos;

    const int b = blockIdx.x >> 5;
    const int s = blockIdx.x & 31;
    const int tid = threadIdx.x;

    if (blockIdx.x == 0 && tid == 0) {      // reset tail accumulators for this call
        ctrl[0] = 0.0f; ctrl[1] = 0.0f; ((unsigned*)ctrl)[2] = 0u;
    }
    if (tid == 0) { cnt = 0; firstpos = 0xFFFFFFFFu; }
    __syncthreads();

    const int* srow = sid + b * T_DIM;
    unsigned myfirst = 0xFFFFFFFFu;
    for (int t = tid; t < T_DIM; t += 256) {
        if (srow[t] == s + 1) {
            int idx = atomicAdd(&cnt, 1);   // LDS atomic
            list[idx] = t;
            if ((unsigned)t < myfirst) myfirst = (unsigned)t;
        }
    }
    if (myfirst != 0xFFFFFFFFu) atomicMin(&firstpos, myfirst);
    __syncthreads();

    const int n = cnt;
    const float4* xb = (const float4*)(x + (size_t)b * T_DIM * D_DIM);
    const int dcol = tid;
    float4 acc = {0.f, 0.f, 0.f, 0.f};

    int i = 0;
    for (; i + 8 <= n; i += 8) {
        int t0 = list[i],     t1 = list[i + 1], t2 = list[i + 2], t3 = list[i + 3];
        int t4 = list[i + 4], t5 = list[i + 5], t6 = list[i + 6], t7 = list[i + 7];
        float4 v0 = xb[(size_t)t0 * (D_DIM / 4) + dcol];
        float4 v1 = xb[(size_t)t1 * (D_DIM / 4) + dcol];
        float4 v2 = xb[(size_t)t2 * (D_DIM / 4) + dcol];
        float4 v3 = xb[(size_t)t3 * (D_DIM / 4) + dcol];
        float4 v4 = xb[(size_t)t4 * (D_DIM / 4) + dcol];
        float4 v5 = xb[(size_t)t5 * (D_DIM / 4) + dcol];
        float4 v6 = xb[(size_t)t6 * (D_DIM / 4) + dcol];
        float4 v7 = xb[(size_t)t7 * (D_DIM / 4) + dcol];
        acc.x += fabsf(v0.x) + fabsf(v1.x) + fabsf(v2.x) + fabsf(v3.x)
               + fabsf(v4.x) + fabsf(v5.x) + fabsf(v6.x) + fabsf(v7.x);
        acc.y += fabsf(v0.y) + fabsf(v1.y) + fabsf(v2.y) + fabsf(v3.y)
               + fabsf(v4.y) + fabsf(v5.y) + fabsf(v6.y) + fabsf(v7.y);
        acc.z += fabsf(v0.z) + fabsf(v1.z) + fabsf(v2.z) + fabsf(v3.z)
               + fabsf(v4.z) + fabsf(v5.z) + fabsf(v6.z) + fabsf(v7.z);
        acc.w += fabsf(v0.w) + fabsf(v1.w) + fabsf(v2.w) + fabsf(v3.w)
               + fabsf(v4.w) + fabsf(v5.w) + fabsf(v6.w) + fabsf(v7.w);
    }
    for (; i + 4 <= n; i += 4) {
        int t0 = list[i], t1 = list[i + 1], t2 = list[i + 2], t3 = list[i + 3];
        float4 v0 = xb[(size_t)t0 * (D_DIM / 4) + dcol];
        float4 v1 = xb[(size_t)t1 * (D_DIM / 4) + dcol];
        float4 v2 = xb[(size_t)t2 * (D_DIM / 4) + dcol];
        float4 v3 = xb[(size_t)t3 * (D_DIM / 4) + dcol];
        acc.x += fabsf(v0.x) + fabsf(v1.x) + fabsf(v2.x) + fabsf(v3.x);
        acc.y += fabsf(v0.y) + fabsf(v1.y) + fabsf(v2.y) + fabsf(v3.y);
        acc.z += fabsf(v0.z) + fabsf(v1.z) + fabsf(v2.z) + fabsf(v3.z);
        acc.w += fabsf(v0.w) + fabsf(v1.w) + fabsf(v2.w) + fabsf(v3.w);
    }
    for (; i < n; ++i) {
        float4 v = xb[(size_t)list[i] * (D_DIM / 4) + dcol];
        acc.x += fabsf(v.x); acc.y += fabsf(v.y);
        acc.z += fabsf(v.z); acc.w += fabsf(v.w);
    }

    const float r = 1.0f / (float)(n > 1 ? n : 1);
    ((float4*)(h + (size_t)blockIdx.x * D_DIM))[dcol] =
        make_float4(acc.x * r, acc.y * r, acc.z * r, acc.w * r);
    if (tid == 0) pos[blockIdx.x] = (n > 0) ? firstpos : (unsigned)T_DIM;
}

// One block per b: argsort pos, pairwise E, per-b loss; atomic-accumulate into
// ctrl; the last block to finish writes out = tot/(num+1e-9). (h/pos coherent
// via the kernel boundary; inter-block comms here via device-scope atomics.)
__global__ __launch_bounds__(256) void k_pairs(const float* __restrict__ h,
                                               const unsigned* __restrict__ pos,
                                               const int* __restrict__ labels,
                                               float* __restrict__ ctrl,
                                               float* __restrict__ out) {
    const int b = blockIdx.x;
    const int tid = threadIdx.x;
    __shared__ unsigned posl[32];
    __shared__ int      ordl[32];
    __shared__ float    El[31];

    if (tid < 32) posl[tid] = pos[(b << 5) + tid];
    __syncthreads();
    if (tid < 32) {                         // stable argsort of pos
        unsigned ps = posl[tid];
        int rk = 0;
        for (int j = 0; j < 32; ++j) {
            unsigned pj = posl[j];
            if (pj < ps || (pj == ps && j < tid)) rk++;
        }
        ordl[rk] = tid;
    }
    __syncthreads();

    const int wave = tid >> 6;
    const int lane = tid & 63;
    for (int p = wave; p < 31; p += 4) {
        int A  = ordl[p];
        int B2 = ordl[p + 1];
        float ssum = 0.0f;
        if (posl[B2] < (unsigned)T_DIM) {
            const float* pa = &h[((size_t)(b << 5) + A)  * D_DIM];
            const float* pb = &h[((size_t)(b << 5) + B2) * D_DIM];
            for (int d = lane * 4; d < D_DIM; d += 256) {
                float4 a4 = *(const float4*)(pa + d);
                float4 b4 = *(const float4*)(pb + d);
                float d0 = fmaxf(a4.x - b4.x, 0.f);
                float d1 = fmaxf(a4.y - b4.y, 0.f);
                float d2 = fmaxf(a4.z - b4.z, 0.f);
                float d3 = fmaxf(a4.w - b4.w, 0.f);
                ssum += d0 * d0 + d1 * d1 + d2 * d2 + d3 * d3;
            }
        }
        #pragma unroll
        for (int off = 32; off; off >>= 1) ssum += __shfl_down(ssum, off);
        if (lane == 0) El[p] = ssum * (1.0f / D_DIM);
    }
    __syncthreads();

    if (tid == 0) {
        float lpos = 0.f, lneg = 0.f;
        int np = 0, ni = 0, nn = 0;
        for (int s2 = 0; s2 < 32; ++s2) nn += (posl[s2] < T_DIM) ? 1 : 0;
        for (int p = 0; p < 31; ++p) {
            int A  = ordl[p];
            int B2 = ordl[p + 1];
            if (posl[B2] < (unsigned)T_DIM) {    // pair_valid
                float Ev = El[p];
                np++; lpos += Ev;
                if (A > B2) { ni++; lneg += fmaxf(1.0f - Ev, 0.0f); }  // ALPHA=1
            }
        }
        float loss_pos = lpos / (float)(np > 1 ? np : 1);
        float loss_neg = lneg / (float)(ni > 1 ? ni : 1);
        int lab = labels[b];
        bool pc = (lab == 1) && (nn >= 2);
        bool nc = (lab == 0) && (ni > 0);
        float contrib = (pc ? loss_pos : 0.0f) + (nc ? loss_neg : 0.0f);
        float cf = (float)((pc ? 1 : 0) + (nc ? 1 : 0));

        atomicAdd(&ctrl[0], contrib);
        atomicAdd(&ctrl[1], cf);
        __threadfence();
        unsigned old = atomicAdd(&((unsigned*)ctrl)[2], 1u);
        if (old == (unsigned)(B_DIM - 1)) {      // last block overall
            __threadfence();
            float tot = atomicAdd(&ctrl[0], 0.0f);   // coherent reads
            float num = atomicAdd(&ctrl[1], 0.0f);
            out[0] = tot / (num + 1e-9f);
        }
    }
}

extern "C" void kernel_launch(void* const* d_in, const int* in_sizes, int n_in,
                              void* d_out, int out_size, void* d_ws, size_t ws_size,
                              hipStream_t stream) {
    const float* x      = (const float*)d_in[0];
    const int*   sid    = (const int*)d_in[1];
    const int*   labels = (const int*)d_in[2];
    float* out = (float*)d_out;
    char*  ws  = (char*)d_ws;

    float*    h    = (float*)(ws + H_OFF);
    unsigned* pos  = (unsigned*)(ws + POS_OFF);
    float*    ctrl = (float*)(ws + CTRL_OFF);

    k_gather<<<B_DIM * S_MAXK, 256, 0, stream>>>(x, sid, h, pos, ctrl);
    k_pairs <<<B_DIM,          256, 0, stream>>>(h, pos, labels, ctrl, out);
}